// Round 7
// baseline (206.264 us; speedup 1.0000x reference)
//
#include <hip/hip_runtime.h>
#include <hip/hip_cooperative_groups.h>

namespace cg = cooperative_groups;

#define NL   128   // rows per line table
#define CL   32    // channels per line table
#define HDIM 128   // hidden dim
#define GRID1 1024 // blocks (must be <= co-resident capacity: 8 blocks/CU * 256 CU)

// ws layout: unsigned long long partials[6][GRID1]  (48 KB, plain stores only)
//   word w of block b at partials[w*GRID1 + b]; words: x_lo,x_hi,y_lo,y_hi,z_lo,z_hi
// No memset needed: every slot is written before it is read.

__global__ __launch_bounds__(256, 8) void fused_coop_kernel(
    const float* __restrict__ coords, long long nflt,
    const float* __restrict__ l0, const float* __restrict__ l1,
    const float* __restrict__ l2,
    const float* __restrict__ w1, const float* __restrict__ b1,
    const float* __restrict__ w2, const float* __restrict__ b2,
    unsigned long long* __restrict__ partials,
    float* __restrict__ out, int out_n)
{
    const int tid = threadIdx.x;
    const int gid = blockIdx.x * blockDim.x + tid;
    const int nthreads = gridDim.x * blockDim.x;
    const int lane = tid & 63;
    const int wave = tid >> 6;

    // ================= Phase 1: mask partials + out-fill =================
    unsigned long long mx0 = 0, mx1 = 0, my0 = 0, my1 = 0, mz0 = 0, mz1 = 0;

    const float4* c4 = (const float4*)coords;
    const long long n4 = nflt >> 2;
    const long long n4tri = (n4 / 3) * 3;

    // 3 consecutive float4s per thread per iter => element dim e%3 is static.
    for (long long base = (long long)gid * 3; base + 2 < n4tri;
         base += (long long)nthreads * 3) {
        float4 a = c4[base + 0];
        float4 b = c4[base + 1];
        float4 c = c4[base + 2];
        float v[12] = {a.x, a.y, a.z, a.w, b.x, b.y, b.z, b.w, c.x, c.y, c.z, c.w};
        #pragma unroll
        for (int e = 0; e < 12; ++e) {
            float fi = rintf((v[e] + 2.0f) * 32.0f);   // (x+D/2)*(Nl/D), half-even
            bool valid = (fi >= 0.0f) && (fi < 128.0f);
            int idx = (int)fi;
            unsigned long long bit = 1ull << (idx & 63);
            unsigned long long blo = (valid && idx < 64) ? bit : 0ull;
            unsigned long long bhi = (valid && idx >= 64) ? bit : 0ull;
            if (e % 3 == 0)      { mx0 |= blo; mx1 |= bhi; }
            else if (e % 3 == 1) { my0 |= blo; my1 |= bhi; }
            else                 { mz0 |= blo; mz1 |= bhi; }
        }
    }
    for (long long f = n4tri * 4 + gid; f < nflt; f += nthreads) {  // tail (unused here)
        float fi = rintf((coords[f] + 2.0f) * 32.0f);
        bool valid = (fi >= 0.0f) && (fi < 128.0f);
        int idx = (int)fi;
        unsigned long long bit = 1ull << (idx & 63);
        unsigned long long blo = (valid && idx < 64) ? bit : 0ull;
        unsigned long long bhi = (valid && idx >= 64) ? bit : 0ull;
        int d = (int)(f % 3);
        if (d == 0)      { mx0 |= blo; mx1 |= bhi; }
        else if (d == 1) { my0 |= blo; my1 |= bhi; }
        else             { mz0 |= blo; mz1 |= bhi; }
    }

    #pragma unroll
    for (int off = 1; off < 64; off <<= 1) {
        mx0 |= __shfl_xor(mx0, off);
        mx1 |= __shfl_xor(mx1, off);
        my0 |= __shfl_xor(my0, off);
        my1 |= __shfl_xor(my1, off);
        mz0 |= __shfl_xor(mz0, off);
        mz1 |= __shfl_xor(mz1, off);
    }

    __shared__ unsigned long long sm[4][6];
    if (lane == 0) {
        sm[wave][0] = mx0; sm[wave][1] = mx1;
        sm[wave][2] = my0; sm[wave][3] = my1;
        sm[wave][4] = mz0; sm[wave][5] = mz1;
    }
    __syncthreads();
    if (tid < 6) {
        // Plain store, block-private slot (distinct addresses; no atomics).
        unsigned long long r = sm[0][tid] | sm[1][tid] | sm[2][tid] | sm[3][tid];
        partials[tid * GRID1 + blockIdx.x] = r;
    }

    // Constant for rows >= NL, fill out[NL..out_n).
    float p = fmaxf(b1[lane], 0.0f) * w2[lane]
            + fmaxf(b1[lane + 64], 0.0f) * w2[lane + 64];
    #pragma unroll
    for (int off = 1; off < 64; off <<= 1) p += __shfl_xor(p, off);
    const float constant = p + b2[0];

    const int n4o = (out_n - NL) >> 2;
    float4* o4 = (float4*)(out + NL);
    const float4 cv = make_float4(constant, constant, constant, constant);
    for (int i = gid; i < n4o; i += nthreads) o4[i] = cv;
    for (int i = NL + (n4o << 2) + gid; i < out_n; i += nthreads) out[i] = constant;

    // Release this block's partial stores (stores were issued by wave 0 =
    // tid0's wave; threadfence waits the wave's vmcnt then writes back L2).
    __syncthreads();
    if (tid == 0) __threadfence();

    // ================= Grid-wide barrier =================
    cg::this_grid().sync();

    // ================= Phase 2: distributed head (blocks 0..127) ==========
    if (blockIdx.x >= NL) return;
    const int r = blockIdx.x;
    const int word = r >> 6;
    const int bit = r & 63;

    // OR-reduce the 3 words this row needs over GRID1 block-partials.
    unsigned long long vx = 0, vy = 0, vz = 0;
    for (int i = tid; i < GRID1; i += 256) {
        vx |= partials[(0 + word) * GRID1 + i];
        vy |= partials[(2 + word) * GRID1 + i];
        vz |= partials[(4 + word) * GRID1 + i];
    }
    #pragma unroll
    for (int off = 1; off < 64; off <<= 1) {
        vx |= __shfl_xor(vx, off);
        vy |= __shfl_xor(vy, off);
        vz |= __shfl_xor(vz, off);
    }
    __shared__ unsigned long long sred[4][3];
    __shared__ float fsum[2];
    if (lane == 0) { sred[wave][0] = vx; sred[wave][1] = vy; sred[wave][2] = vz; }
    __syncthreads();
    vx = sred[0][0] | sred[1][0] | sred[2][0] | sred[3][0];
    vy = sred[0][1] | sred[1][1] | sred[2][1] | sred[3][1];
    vz = sred[0][2] | sred[1][2] | sred[2][2] | sred[3][2];

    if (tid >= HDIM) return;   // 128 threads compute; j = tid

    const float ox = (float)((vx >> bit) & 1ull);
    const float oy = (float)((vy >> bit) & 1ull);
    const float oz = (float)((vz >> bit) & 1ull);

    const float R  = 0.4f;
    const float R2 = (float)(0.4 * 0.4);

    float feats[CL];
    const float4* l0v = (const float4*)(l0 + r * CL);
    const float4* l1v = (const float4*)(l1 + r * CL);
    const float4* l2v = (const float4*)(l2 + r * CL);
    #pragma unroll
    for (int q4 = 0; q4 < CL / 4; ++q4) {
        float4 a = l0v[q4];
        float4 b = l1v[q4];
        float4 c = l2v[q4];
        float xs[4] = {a.x * ox, a.y * ox, a.z * ox, a.w * ox};
        float ys[4] = {b.x * oy, b.y * oy, b.z * oy, b.w * oy};
        float zs[4] = {c.x * oz, c.y * oz, c.z * oz, c.w * oz};
        #pragma unroll
        for (int q = 0; q < 4; ++q) {
            float x = xs[q], y = ys[q], z = zs[q];
            feats[q4 * 4 + q] = (x + y + z)
                              + (x * y + x * z + y * z) / R
                              + x * y * z / R2;
        }
    }

    // Hidden unit j = tid: dot(feats, w1[j,:]) + b1[j], relu, * w2[j].
    const float4* w1v = (const float4*)(w1 + tid * CL);
    float acc = b1[tid];
    #pragma unroll
    for (int q4 = 0; q4 < CL / 4; ++q4) {
        float4 w = w1v[q4];
        acc += feats[q4 * 4 + 0] * w.x;
        acc += feats[q4 * 4 + 1] * w.y;
        acc += feats[q4 * 4 + 2] * w.z;
        acc += feats[q4 * 4 + 3] * w.w;
    }
    float h = fmaxf(acc, 0.0f) * w2[tid];

    #pragma unroll
    for (int off = 1; off < 64; off <<= 1) h += __shfl_xor(h, off);
    if (lane == 0) fsum[wave] = h;
    __syncthreads();
    if (tid == 0) out[r] = fsum[0] + fsum[1] + b2[0];
}

extern "C" void kernel_launch(void* const* d_in, const int* in_sizes, int n_in,
                              void* d_out, int out_size, void* d_ws, size_t ws_size,
                              hipStream_t stream) {
    const float* coords = (const float*)d_in[0];
    const float* l0 = (const float*)d_in[1];
    const float* l1 = (const float*)d_in[2];
    const float* l2 = (const float*)d_in[3];
    const float* w1 = (const float*)d_in[4];
    const float* b1 = (const float*)d_in[5];
    const float* w2 = (const float*)d_in[6];
    const float* b2 = (const float*)d_in[7];
    float* out = (float*)d_out;
    unsigned long long* partials = (unsigned long long*)d_ws;
    long long nflt = (long long)in_sizes[0];
    int out_n = out_size;

    void* args[] = {
        (void*)&coords, (void*)&nflt,
        (void*)&l0, (void*)&l1, (void*)&l2,
        (void*)&w1, (void*)&b1, (void*)&w2, (void*)&b2,
        (void*)&partials, (void*)&out, (void*)&out_n
    };
    hipLaunchCooperativeKernel((const void*)fused_coop_kernel,
                               dim3(GRID1), dim3(256), args, 0, stream);
}

// Round 8
// 105.706 us; speedup vs baseline: 1.9513x; 1.9513x over previous
//
#include <hip/hip_runtime.h>

#define NL    128   // rows per line table
#define CL    32    // channels per line table
#define HDIM  128   // hidden dim
#define GRID1 1024  // blocks; must be multiple of NSHARD; <= co-resident capacity
#define NSHARD 64   // mask/counter shards (one 64-B line each)

// ws layout (u64):
//   smask[NSHARD][8] : shard s line; words 0..5 = {x_lo,x_hi,y_lo,y_hi,z_lo,z_hi}
//   scnt [NSHARD][8] : shard s arrival counter in word 0
// kernel_launch memsets the first 8 KB to 0 each call (atomics need zero-init).
// All cross-block communication is via atomics (device coherent point).
// No __threadfence, no grid.sync (both measured at ~60-90 us serialization).

__global__ __launch_bounds__(256) void fused_shard_kernel(
    const float* __restrict__ coords, long long nflt,
    const float* __restrict__ l0, const float* __restrict__ l1,
    const float* __restrict__ l2,
    const float* __restrict__ w1, const float* __restrict__ b1,
    const float* __restrict__ w2, const float* __restrict__ b2,
    unsigned long long* __restrict__ gws,
    float* __restrict__ out, int out_n)
{
    const int tid = threadIdx.x;
    const int gid = blockIdx.x * blockDim.x + tid;
    const int nthreads = gridDim.x * blockDim.x;
    const int lane = tid & 63;
    const int wave = tid >> 6;

    unsigned long long* smask = gws;                 // [NSHARD][8]
    unsigned long long* scnt  = gws + NSHARD * 8;    // [NSHARD][8]

    // ================= Phase 1: occupancy-mask partials =================
    unsigned long long mx0 = 0, mx1 = 0, my0 = 0, my1 = 0, mz0 = 0, mz1 = 0;

    const float4* c4 = (const float4*)coords;
    const long long n4 = nflt >> 2;
    const long long n4tri = (n4 / 3) * 3;

    // 3 consecutive float4s per thread per iter => element dim e%3 is static.
    for (long long base = (long long)gid * 3; base + 2 < n4tri;
         base += (long long)nthreads * 3) {
        float4 a = c4[base + 0];
        float4 b = c4[base + 1];
        float4 c = c4[base + 2];
        float v[12] = {a.x, a.y, a.z, a.w, b.x, b.y, b.z, b.w, c.x, c.y, c.z, c.w};
        #pragma unroll
        for (int e = 0; e < 12; ++e) {
            float fi = rintf((v[e] + 2.0f) * 32.0f);   // (x+D/2)*(Nl/D), half-even
            bool valid = (fi >= 0.0f) && (fi < 128.0f);
            int idx = (int)fi;
            unsigned long long bit = 1ull << (idx & 63);
            unsigned long long blo = (valid && idx < 64) ? bit : 0ull;
            unsigned long long bhi = (valid && idx >= 64) ? bit : 0ull;
            if (e % 3 == 0)      { mx0 |= blo; mx1 |= bhi; }
            else if (e % 3 == 1) { my0 |= blo; my1 |= bhi; }
            else                 { mz0 |= blo; mz1 |= bhi; }
        }
    }
    for (long long f = n4tri * 4 + gid; f < nflt; f += nthreads) {  // tail (unused here)
        float fi = rintf((coords[f] + 2.0f) * 32.0f);
        bool valid = (fi >= 0.0f) && (fi < 128.0f);
        int idx = (int)fi;
        unsigned long long bit = 1ull << (idx & 63);
        unsigned long long blo = (valid && idx < 64) ? bit : 0ull;
        unsigned long long bhi = (valid && idx >= 64) ? bit : 0ull;
        int d = (int)(f % 3);
        if (d == 0)      { mx0 |= blo; mx1 |= bhi; }
        else if (d == 1) { my0 |= blo; my1 |= bhi; }
        else             { mz0 |= blo; mz1 |= bhi; }
    }

    #pragma unroll
    for (int off = 1; off < 64; off <<= 1) {
        mx0 |= __shfl_xor(mx0, off);
        mx1 |= __shfl_xor(mx1, off);
        my0 |= __shfl_xor(my0, off);
        my1 |= __shfl_xor(my1, off);
        mz0 |= __shfl_xor(mz0, off);
        mz1 |= __shfl_xor(mz1, off);
    }

    __shared__ unsigned long long sm[4][6];
    if (lane == 0) {
        sm[wave][0] = mx0; sm[wave][1] = mx1;
        sm[wave][2] = my0; sm[wave][3] = my1;
        sm[wave][4] = mz0; sm[wave][5] = mz1;
    }
    __syncthreads();

    // Publish: 6 atomicOr into this block's shard line, then (after the wave's
    // VMEM acks) one arrival-count add. Lanes 0..6 are all in wave 0, so
    // s_waitcnt vmcnt(0) (proven ~free in round 5) orders Or -> Add.
    const int shard = blockIdx.x & (NSHARD - 1);
    if (tid < 6) {
        unsigned long long r = sm[0][tid] | sm[1][tid] | sm[2][tid] | sm[3][tid];
        atomicOr(&smask[shard * 8 + tid], r);
    }
    if (wave == 0) {
        asm volatile("s_waitcnt vmcnt(0)" ::: "memory");
        if (tid == 0) atomicAdd(&scnt[shard * 8], 1ull);
    }

    // ---- Constant for rows >= NL, fill out[NL..out_n) ----
    float p = fmaxf(b1[lane], 0.0f) * w2[lane]
            + fmaxf(b1[lane + 64], 0.0f) * w2[lane + 64];
    #pragma unroll
    for (int off = 1; off < 64; off <<= 1) p += __shfl_xor(p, off);
    const float constant = p + b2[0];

    const int n4o = (out_n - NL) >> 2;
    float4* o4 = (float4*)(out + NL);
    const float4 cv = make_float4(constant, constant, constant, constant);
    for (int i = gid; i < n4o; i += nthreads) o4[i] = cv;
    for (int i = NL + (n4o << 2) + gid; i < out_n; i += nthreads) out[i] = constant;

    // ================= Phase 2: head blocks 0..127 =================
    if (blockIdx.x >= NL) return;
    const int r = blockIdx.x;
    const int word = r >> 6;
    const int bit = r & 63;
    const unsigned long long quota = (unsigned long long)(GRID1 / NSHARD);

    // Poll the 64 shard counters (wave 0: lane t owns counter t). Atomic reads
    // execute at the coherent point -- no fence needed.
    __shared__ int sdone;
    if (tid == 0) sdone = 0;
    __syncthreads();
    if (wave == 0) {
        int iters = 0;
        for (;;) {
            unsigned long long c = atomicAdd(&scnt[lane * 8], 0ull);
            if (__all(c >= quota)) break;
            if (++iters > 1000000) break;          // bailout: no GPU hang
            __builtin_amdgcn_s_sleep(16);
        }
        if (lane == 0) sdone = 1;
    }
    __syncthreads();
    (void)sdone;

    // Gather sharded masks: thread t (t<192) reads word (wsel*2+word) of shard
    // (t&63); wave w OR-reduces its 64 shard values -> one word per wave.
    const int wsel = tid >> 6;          // 0,1,2 used
    unsigned long long gv = 0;
    if (wsel < 3) gv = atomicAdd(&smask[(tid & 63) * 8 + (wsel * 2 + word)], 0ull);
    #pragma unroll
    for (int off = 1; off < 64; off <<= 1) gv |= __shfl_xor(gv, off);
    __shared__ unsigned long long sred[3];
    __shared__ float fsum[2];
    if (wsel < 3 && lane == 0) sred[wsel] = gv;
    __syncthreads();
    const unsigned long long vx = sred[0];
    const unsigned long long vy = sred[1];
    const unsigned long long vz = sred[2];

    if (tid >= HDIM) return;   // 128 threads compute; hidden unit j = tid

    const float ox = (float)((vx >> bit) & 1ull);
    const float oy = (float)((vy >> bit) & 1ull);
    const float oz = (float)((vz >> bit) & 1ull);

    const float R  = 0.4f;
    const float R2 = (float)(0.4 * 0.4);

    float feats[CL];
    const float4* l0v = (const float4*)(l0 + r * CL);
    const float4* l1v = (const float4*)(l1 + r * CL);
    const float4* l2v = (const float4*)(l2 + r * CL);
    #pragma unroll
    for (int q4 = 0; q4 < CL / 4; ++q4) {
        float4 a = l0v[q4];
        float4 b = l1v[q4];
        float4 c = l2v[q4];
        float xs[4] = {a.x * ox, a.y * ox, a.z * ox, a.w * ox};
        float ys[4] = {b.x * oy, b.y * oy, b.z * oy, b.w * oy};
        float zs[4] = {c.x * oz, c.y * oz, c.z * oz, c.w * oz};
        #pragma unroll
        for (int q = 0; q < 4; ++q) {
            float x = xs[q], y = ys[q], z = zs[q];
            feats[q4 * 4 + q] = (x + y + z)
                              + (x * y + x * z + y * z) / R
                              + x * y * z / R2;
        }
    }

    const float4* w1v = (const float4*)(w1 + tid * CL);
    float acc = b1[tid];
    #pragma unroll
    for (int q4 = 0; q4 < CL / 4; ++q4) {
        float4 w = w1v[q4];
        acc += feats[q4 * 4 + 0] * w.x;
        acc += feats[q4 * 4 + 1] * w.y;
        acc += feats[q4 * 4 + 2] * w.z;
        acc += feats[q4 * 4 + 3] * w.w;
    }
    float h = fmaxf(acc, 0.0f) * w2[tid];

    #pragma unroll
    for (int off = 1; off < 64; off <<= 1) h += __shfl_xor(h, off);
    if (lane == 0) fsum[wave] = h;
    __syncthreads();
    if (tid == 0) out[r] = fsum[0] + fsum[1] + b2[0];
}

extern "C" void kernel_launch(void* const* d_in, const int* in_sizes, int n_in,
                              void* d_out, int out_size, void* d_ws, size_t ws_size,
                              hipStream_t stream) {
    const float* coords = (const float*)d_in[0];
    const float* l0 = (const float*)d_in[1];
    const float* l1 = (const float*)d_in[2];
    const float* l2 = (const float*)d_in[3];
    const float* w1 = (const float*)d_in[4];
    const float* b1 = (const float*)d_in[5];
    const float* w2 = (const float*)d_in[6];
    const float* b2 = (const float*)d_in[7];
    float* out = (float*)d_out;
    unsigned long long* gws = (unsigned long long*)d_ws;
    const long long nflt = (long long)in_sizes[0];

    // zero smask[64][8] + scnt[64][8] = 8 KB
    hipMemsetAsync(d_ws, 0, 2 * NSHARD * 8 * sizeof(unsigned long long), stream);
    fused_shard_kernel<<<GRID1, 256, 0, stream>>>(coords, nflt, l0, l1, l2,
                                                  w1, b1, w2, b2, gws,
                                                  out, out_size);
}

// Round 9
// 104.550 us; speedup vs baseline: 1.9729x; 1.0111x over previous
//
#include <hip/hip_runtime.h>

#define NL    128   // rows per line table
#define CL    32    // channels per line table
#define HDIM  128   // hidden dim
#define GRID1 1024  // blocks; 4 waves/block -> 4096 waves, fully co-resident (cap 8192)

// ws layout (u64), NO initialization required (write-before-read via flags):
//   partials[6][GRID1] : word w of block b at w*GRID1+b  (x_lo,x_hi,y_lo,y_hi,z_lo,z_hi)
//   flags[GRID1]       : at 6*GRID1 + b ; set to 1 after block b's partials are
//                        globally visible. Harness poison 0xAAAA... != 1.
// All cross-block data moves via relaxed AGENT-scope atomic load/store: single
// instructions at the device-coherent point. No RMW pileup (rounds 4/5/7 showed
// same-line atomics / threadfence / grid.sync cost 60-90 us), no memset node.

__device__ __forceinline__ void agent_store_u64(unsigned long long* p, unsigned long long v) {
    __hip_atomic_store(p, v, __ATOMIC_RELAXED, __HIP_MEMORY_SCOPE_AGENT);
}
__device__ __forceinline__ unsigned long long agent_load_u64(const unsigned long long* p) {
    return __hip_atomic_load(p, __ATOMIC_RELAXED, __HIP_MEMORY_SCOPE_AGENT);
}

__global__ __launch_bounds__(256) void fused_flag_kernel(
    const float* __restrict__ coords, long long nflt,
    const float* __restrict__ l0, const float* __restrict__ l1,
    const float* __restrict__ l2,
    const float* __restrict__ w1, const float* __restrict__ b1,
    const float* __restrict__ w2, const float* __restrict__ b2,
    unsigned long long* __restrict__ gws,
    float* __restrict__ out, int out_n)
{
    const int tid = threadIdx.x;
    const int gid = blockIdx.x * blockDim.x + tid;
    const int nthreads = gridDim.x * blockDim.x;
    const int lane = tid & 63;
    const int wave = tid >> 6;

    unsigned long long* partials = gws;            // [6][GRID1]
    unsigned long long* flags    = gws + 6 * GRID1; // [GRID1]

    // ================= Phase 1: occupancy-mask partials =================
    unsigned long long mx0 = 0, mx1 = 0, my0 = 0, my1 = 0, mz0 = 0, mz1 = 0;

    const float4* c4 = (const float4*)coords;
    const long long n4 = nflt >> 2;
    const long long n4tri = (n4 / 3) * 3;

    // 3 consecutive float4s per thread per iter => element dim e%3 is static.
    for (long long base = (long long)gid * 3; base + 2 < n4tri;
         base += (long long)nthreads * 3) {
        float4 a = c4[base + 0];
        float4 b = c4[base + 1];
        float4 c = c4[base + 2];
        float v[12] = {a.x, a.y, a.z, a.w, b.x, b.y, b.z, b.w, c.x, c.y, c.z, c.w};
        #pragma unroll
        for (int e = 0; e < 12; ++e) {
            float fi = rintf((v[e] + 2.0f) * 32.0f);   // (x+D/2)*(Nl/D), half-even
            bool valid = (fi >= 0.0f) && (fi < 128.0f);
            int idx = (int)fi;
            unsigned long long bit = 1ull << (idx & 63);
            unsigned long long blo = (valid && idx < 64) ? bit : 0ull;
            unsigned long long bhi = (valid && idx >= 64) ? bit : 0ull;
            if (e % 3 == 0)      { mx0 |= blo; mx1 |= bhi; }
            else if (e % 3 == 1) { my0 |= blo; my1 |= bhi; }
            else                 { mz0 |= blo; mz1 |= bhi; }
        }
    }
    for (long long f = n4tri * 4 + gid; f < nflt; f += nthreads) {  // tail (unused here)
        float fi = rintf((coords[f] + 2.0f) * 32.0f);
        bool valid = (fi >= 0.0f) && (fi < 128.0f);
        int idx = (int)fi;
        unsigned long long bit = 1ull << (idx & 63);
        unsigned long long blo = (valid && idx < 64) ? bit : 0ull;
        unsigned long long bhi = (valid && idx >= 64) ? bit : 0ull;
        int d = (int)(f % 3);
        if (d == 0)      { mx0 |= blo; mx1 |= bhi; }
        else if (d == 1) { my0 |= blo; my1 |= bhi; }
        else             { mz0 |= blo; mz1 |= bhi; }
    }

    #pragma unroll
    for (int off = 1; off < 64; off <<= 1) {
        mx0 |= __shfl_xor(mx0, off);
        mx1 |= __shfl_xor(mx1, off);
        my0 |= __shfl_xor(my0, off);
        my1 |= __shfl_xor(my1, off);
        mz0 |= __shfl_xor(mz0, off);
        mz1 |= __shfl_xor(mz1, off);
    }

    __shared__ unsigned long long sm[4][6];
    if (lane == 0) {
        sm[wave][0] = mx0; sm[wave][1] = mx1;
        sm[wave][2] = my0; sm[wave][3] = my1;
        sm[wave][4] = mz0; sm[wave][5] = mz1;
    }
    __syncthreads();

    // Publish: 6 agent-scope stores to this block's PRIVATE slots (no
    // contention, no init needed), vmcnt(0) to wait their coherent-point acks
    // (lanes 0..5 and tid 0 are all wave 0), then flag := 1.
    if (tid < 6) {
        unsigned long long r = sm[0][tid] | sm[1][tid] | sm[2][tid] | sm[3][tid];
        agent_store_u64(&partials[tid * GRID1 + blockIdx.x], r);
    }
    if (wave == 0) {
        asm volatile("s_waitcnt vmcnt(0)" ::: "memory");
        if (tid == 0) agent_store_u64(&flags[blockIdx.x], 1ull);
    }

    // ---- Constant for rows >= NL, fill out[NL..out_n) ----
    float p = fmaxf(b1[lane], 0.0f) * w2[lane]
            + fmaxf(b1[lane + 64], 0.0f) * w2[lane + 64];
    #pragma unroll
    for (int off = 1; off < 64; off <<= 1) p += __shfl_xor(p, off);
    const float constant = p + b2[0];

    const int n4o = (out_n - NL) >> 2;
    float4* o4 = (float4*)(out + NL);
    const float4 cv = make_float4(constant, constant, constant, constant);
    for (int i = gid; i < n4o; i += nthreads) o4[i] = cv;
    for (int i = NL + (n4o << 2) + gid; i < out_n; i += nthreads) out[i] = constant;

    // ================= Phase 2: head blocks 0..127 =================
    if (blockIdx.x >= NL) return;
    const int r = blockIdx.x;
    const int word = r >> 6;
    const int bit = r & 63;

    // Wave 0 polls all GRID1 flags (lane l owns flags[l + 64k], k=0..15).
    if (wave == 0) {
        int iters = 0;
        for (;;) {
            bool mine = true;
            #pragma unroll
            for (int k = 0; k < GRID1 / 64; ++k)
                mine &= (agent_load_u64(&flags[lane + 64 * k]) == 1ull);
            if (__all(mine)) break;
            if (++iters > 1000000) break;          // bailout: never hang the GPU
            __builtin_amdgcn_s_sleep(8);
        }
    }
    __syncthreads();   // all waves wait until wave 0 saw every flag

    // Gather: OR-reduce the 3 needed words over GRID1 slots with 256 threads.
    unsigned long long vx = 0, vy = 0, vz = 0;
    for (int i = tid; i < GRID1; i += 256) {
        vx |= agent_load_u64(&partials[(0 + word) * GRID1 + i]);
        vy |= agent_load_u64(&partials[(2 + word) * GRID1 + i]);
        vz |= agent_load_u64(&partials[(4 + word) * GRID1 + i]);
    }
    #pragma unroll
    for (int off = 1; off < 64; off <<= 1) {
        vx |= __shfl_xor(vx, off);
        vy |= __shfl_xor(vy, off);
        vz |= __shfl_xor(vz, off);
    }
    __shared__ unsigned long long sred[4][3];
    __shared__ float fsum[2];
    if (lane == 0) { sred[wave][0] = vx; sred[wave][1] = vy; sred[wave][2] = vz; }
    __syncthreads();
    vx = sred[0][0] | sred[1][0] | sred[2][0] | sred[3][0];
    vy = sred[0][1] | sred[1][1] | sred[2][1] | sred[3][1];
    vz = sred[0][2] | sred[1][2] | sred[2][2] | sred[3][2];

    if (tid >= HDIM) return;   // 128 threads compute; hidden unit j = tid

    const float ox = (float)((vx >> bit) & 1ull);
    const float oy = (float)((vy >> bit) & 1ull);
    const float oz = (float)((vz >> bit) & 1ull);

    const float R  = 0.4f;
    const float R2 = (float)(0.4 * 0.4);

    float feats[CL];
    const float4* l0v = (const float4*)(l0 + r * CL);
    const float4* l1v = (const float4*)(l1 + r * CL);
    const float4* l2v = (const float4*)(l2 + r * CL);
    #pragma unroll
    for (int q4 = 0; q4 < CL / 4; ++q4) {
        float4 a = l0v[q4];
        float4 b = l1v[q4];
        float4 c = l2v[q4];
        float xs[4] = {a.x * ox, a.y * ox, a.z * ox, a.w * ox};
        float ys[4] = {b.x * oy, b.y * oy, b.z * oy, b.w * oy};
        float zs[4] = {c.x * oz, c.y * oz, c.z * oz, c.w * oz};
        #pragma unroll
        for (int q = 0; q < 4; ++q) {
            float x = xs[q], y = ys[q], z = zs[q];
            feats[q4 * 4 + q] = (x + y + z)
                              + (x * y + x * z + y * z) / R
                              + x * y * z / R2;
        }
    }

    const float4* w1v = (const float4*)(w1 + tid * CL);
    float acc = b1[tid];
    #pragma unroll
    for (int q4 = 0; q4 < CL / 4; ++q4) {
        float4 w = w1v[q4];
        acc += feats[q4 * 4 + 0] * w.x;
        acc += feats[q4 * 4 + 1] * w.y;
        acc += feats[q4 * 4 + 2] * w.z;
        acc += feats[q4 * 4 + 3] * w.w;
    }
    float h = fmaxf(acc, 0.0f) * w2[tid];

    #pragma unroll
    for (int off = 1; off < 64; off <<= 1) h += __shfl_xor(h, off);
    if (lane == 0) fsum[wave] = h;
    __syncthreads();
    if (tid == 0) out[r] = fsum[0] + fsum[1] + b2[0];
}

extern "C" void kernel_launch(void* const* d_in, const int* in_sizes, int n_in,
                              void* d_out, int out_size, void* d_ws, size_t ws_size,
                              hipStream_t stream) {
    const float* coords = (const float*)d_in[0];
    const float* l0 = (const float*)d_in[1];
    const float* l1 = (const float*)d_in[2];
    const float* l2 = (const float*)d_in[3];
    const float* w1 = (const float*)d_in[4];
    const float* b1 = (const float*)d_in[5];
    const float* w2 = (const float*)d_in[6];
    const float* b2 = (const float*)d_in[7];
    float* out = (float*)d_out;
    unsigned long long* gws = (unsigned long long*)d_ws;
    const long long nflt = (long long)in_sizes[0];

    // Single node: no memset (flags/partials are write-before-read; poison-safe).
    fused_flag_kernel<<<GRID1, 256, 0, stream>>>(coords, nflt, l0, l1, l2,
                                                 w1, b1, w2, b2, gws,
                                                 out, out_size);
}